// Round 1
// baseline (406.470 us; speedup 1.0000x reference)
//
#include <hip/hip_runtime.h>

#define NN 8192

// Kernel 1: all O(N) work — dU, dI, and the local part of dV.
// out layout: out[3j]=dU, out[3j+1]=dI, out[3j+2]=dV (coupling added later).
__global__ __launch_bounds__(256) void init_kernel(
    const float* __restrict__ state,
    const float* __restrict__ betas,
    const float* __restrict__ deltas,
    const float* __restrict__ cs,
    const float* __restrict__ ps,
    const float* __restrict__ ts,
    float* __restrict__ out)
{
    int j = blockIdx.x * 256 + threadIdx.x;
    float U = state[3 * j + 0];
    float I = state[3 * j + 1];
    float V = state[3 * j + 2];
    float beta  = betas[j]  * betas[j];
    float delta = deltas[j] * deltas[j];
    float c     = cs[j]     * cs[j];
    float p     = ps[j]     * ps[j];
    float infect = beta * U * V;
    float diag = ts[(size_t)j * NN + j];   // ts[j,j]
    out[3 * j + 0] = -infect;
    out[3 * j + 1] = infect - delta * I;
    out[3 * j + 2] = p * I - c * V - diag * V;  // coupling matvec added by kernel 2
}

// Kernel 2: coupling[j] = sum_i ts[i*N + j] * V[i], accumulated into out[3j+2].
// Row-major coalesced reads of ts (float4 per lane = 16B). Grid:
//   8 column-chunks (1024 cols each: 256 threads x 4 cols) x 128 row-chunks (64 rows each)
// = 1024 blocks -> 4 blocks/CU, 16 waves/CU. Each output location receives
// 128 float atomicAdds (order nondeterministic; threshold is ~42 on |coupling|~2048).
__global__ __launch_bounds__(256) void matvec_kernel(
    const float* __restrict__ ts,
    const float* __restrict__ state,
    float* __restrict__ out)
{
    const int colChunk = blockIdx.x & 7;        // 0..7
    const int rowChunk = blockIdx.x >> 3;       // 0..127
    const int j0 = colChunk * 1024 + threadIdx.x * 4;
    const int r0 = rowChunk * 64;

    const float* tsp = ts + (size_t)r0 * NN + j0;
    float4 acc = make_float4(0.f, 0.f, 0.f, 0.f);

#pragma unroll 4
    for (int ii = 0; ii < 64; ++ii) {
        float v = state[3 * (r0 + ii) + 2];     // block-uniform -> scalar load
        float4 t = *(const float4*)(tsp + (size_t)ii * NN);
        acc.x += t.x * v;
        acc.y += t.y * v;
        acc.z += t.z * v;
        acc.w += t.w * v;
    }

    atomicAdd(&out[3 * (j0 + 0) + 2], acc.x);
    atomicAdd(&out[3 * (j0 + 1) + 2], acc.y);
    atomicAdd(&out[3 * (j0 + 2) + 2], acc.z);
    atomicAdd(&out[3 * (j0 + 3) + 2], acc.w);
}

extern "C" void kernel_launch(void* const* d_in, const int* in_sizes, int n_in,
                              void* d_out, int out_size, void* d_ws, size_t ws_size,
                              hipStream_t stream) {
    // setup_inputs order: t(0), state(1), betas(2), deltas(3), cs(4), ps(5), ts(6)
    const float* state  = (const float*)d_in[1];
    const float* betas  = (const float*)d_in[2];
    const float* deltas = (const float*)d_in[3];
    const float* cs     = (const float*)d_in[4];
    const float* ps     = (const float*)d_in[5];
    const float* ts     = (const float*)d_in[6];
    float* out = (float*)d_out;

    init_kernel<<<NN / 256, 256, 0, stream>>>(state, betas, deltas, cs, ps, ts, out);
    matvec_kernel<<<1024, 256, 0, stream>>>(ts, state, out);
}

// Round 2
// 406.133 us; speedup vs baseline: 1.0008x; 1.0008x over previous
//
#include <hip/hip_runtime.h>

#define NN 8192

// Kernel 1: all O(N) work — dU, dI, and the local part of dV.
// out layout: out[3j]=dU, out[3j+1]=dI, out[3j+2]=dV (coupling added later).
__global__ __launch_bounds__(256) void init_kernel(
    const float* __restrict__ state,
    const float* __restrict__ betas,
    const float* __restrict__ deltas,
    const float* __restrict__ cs,
    const float* __restrict__ ps,
    const float* __restrict__ ts,
    float* __restrict__ out)
{
    int j = blockIdx.x * 256 + threadIdx.x;
    float U = state[3 * j + 0];
    float I = state[3 * j + 1];
    float V = state[3 * j + 2];
    float beta  = betas[j]  * betas[j];
    float delta = deltas[j] * deltas[j];
    float c     = cs[j]     * cs[j];
    float p     = ps[j]     * ps[j];
    float infect = beta * U * V;
    float diag = ts[(size_t)j * NN + j];   // ts[j,j]
    out[3 * j + 0] = -infect;
    out[3 * j + 1] = infect - delta * I;
    out[3 * j + 2] = p * I - c * V - diag * V;  // coupling matvec added by kernel 2
}

// Kernel 2: coupling[j] = sum_i ts[i*N + j] * V[i], accumulated into out[3j+2].
// Row-major coalesced float4 reads of ts. Grid: 8 col-chunks (1024 cols) x
// 256 row-chunks (32 rows) = 2048 blocks -> 8 blocks/CU, 32 waves/CU.
// V values for the row-chunk are prefetched into registers (uniform s_loads)
// so the FMA loop has no scalar-load dependency chain. unroll 8 keeps ~8
// float4 loads (8 KB/wave) in flight.
__global__ __launch_bounds__(256) void matvec_kernel(
    const float* __restrict__ ts,
    const float* __restrict__ state,
    float* __restrict__ out)
{
    const int colChunk = blockIdx.x & 7;        // 0..7
    const int rowChunk = blockIdx.x >> 3;       // 0..255
    const int j0 = colChunk * 1024 + threadIdx.x * 4;
    const int r0 = rowChunk * 32;

    // Prefetch the 32 V values for this row chunk (block-uniform -> s_loads).
    float v[32];
#pragma unroll
    for (int ii = 0; ii < 32; ++ii)
        v[ii] = state[3 * (r0 + ii) + 2];

    const float* tsp = ts + (size_t)r0 * NN + j0;
    float4 acc = make_float4(0.f, 0.f, 0.f, 0.f);

#pragma unroll 8
    for (int ii = 0; ii < 32; ++ii) {
        float4 t = *(const float4*)(tsp + (size_t)ii * NN);
        acc.x += t.x * v[ii];
        acc.y += t.y * v[ii];
        acc.z += t.z * v[ii];
        acc.w += t.w * v[ii];
    }

    atomicAdd(&out[3 * (j0 + 0) + 2], acc.x);
    atomicAdd(&out[3 * (j0 + 1) + 2], acc.y);
    atomicAdd(&out[3 * (j0 + 2) + 2], acc.z);
    atomicAdd(&out[3 * (j0 + 3) + 2], acc.w);
}

extern "C" void kernel_launch(void* const* d_in, const int* in_sizes, int n_in,
                              void* d_out, int out_size, void* d_ws, size_t ws_size,
                              hipStream_t stream) {
    // setup_inputs order: t(0), state(1), betas(2), deltas(3), cs(4), ps(5), ts(6)
    const float* state  = (const float*)d_in[1];
    const float* betas  = (const float*)d_in[2];
    const float* deltas = (const float*)d_in[3];
    const float* cs     = (const float*)d_in[4];
    const float* ps     = (const float*)d_in[5];
    const float* ts     = (const float*)d_in[6];
    float* out = (float*)d_out;

    init_kernel<<<NN / 256, 256, 0, stream>>>(state, betas, deltas, cs, ps, ts, out);
    matvec_kernel<<<2048, 256, 0, stream>>>(ts, state, out);
}